// Round 6
// baseline (186.641 us; speedup 1.0000x reference)
//
#include <hip/hip_runtime.h>
#include <hip/hip_fp16.h>

// MotifEnergy: fused motif dot -> segment logsumexp over nodes -> graph scatter.
// Shapes: M=1e6 motifs, N=1e5 nodes, R=4, d=16, NTAU=16, G=128.
//
// z = beta*ell is provably bounded -> single-pass sum(exp(z)), lse = log(sum).
//
// Round-6: bytes are exhausted (fp8 cut FETCH 165->135 MB for only -2 us; HBM
// 33%, VALU 12% -- nothing visible saturated). Theory: the floor is same-line
// serialization of the 4M memory-side fp32 atomic RMWs on the 1.6 MB sums
// array (~320 atomics/line; WRITE_SIZE is a constant 47 MB = line rewrite
// churn). Fix under test: 8-way replicated sums (replica = blockIdx&7) to cut
// same-line collision chains 8x. me_node sums the replicas (12.8 MB stream).
//
// ws layout: Q8[6.4MB] | K8[6.4MB] | scal[2] | sums[8][N*R] (12.8MB).

#define RR 4
#define DD 16
#define BETA_MAX 5.0f
#define REP 8

typedef float v2f __attribute__((ext_vector_type(2)));

__device__ __forceinline__ float softplus_f(float x) {
    return log1pf(__expf(x));
}

__device__ __forceinline__ int pack4_fp8(float4 f) {
    int w = 0;
    w = __builtin_amdgcn_cvt_pk_fp8_f32(f.x, f.y, w, false);  // bytes 0,1
    w = __builtin_amdgcn_cvt_pk_fp8_f32(f.z, f.w, w, true);   // bytes 2,3
    return w;
}

// fused: scalars + zero sums replicas/out + convert Q3,K3 fp32->fp8
__global__ void me_init_convert(const float* __restrict__ raw_lam,
                                const float* __restrict__ raw_beta,
                                const float* __restrict__ Q3,
                                const float* __restrict__ K3,
                                int4* __restrict__ Q8, int4* __restrict__ K8,
                                float* __restrict__ scal, float* __restrict__ sums,
                                float* __restrict__ out,
                                int n16each, int nrep, int out_size) {
    int i = blockIdx.x * blockDim.x + threadIdx.x;
    if (i == 0) {
        float beta = fminf(softplus_f(raw_beta[0]), BETA_MAX);
        float lam  = softplus_f(raw_lam[0]);
        scal[0] = beta * 0.125f;   // beta / sqrt(R*d)
        scal[1] = lam / beta;
    }
    if (i < nrep) sums[i] = 0.0f;
    if (i < out_size) out[i] = 0.0f;
    if (i < 2 * n16each) {
        const float* src = (i < n16each) ? Q3 : K3;
        int4*        dst = (i < n16each) ? Q8 : K8;
        int j = (i < n16each) ? i : i - n16each;
        const float4* s4 = (const float4*)src + 4 * (size_t)j;
        int4 o;
        o.x = pack4_fp8(s4[0]);
        o.y = pack4_fp8(s4[1]);
        o.z = pack4_fp8(s4[2]);
        o.w = pack4_fp8(s4[3]);
        dst[j] = o;
    }
}

// 4 lanes per motif: lane k handles r=k; one int4 load = full 16-elem d-row.
__device__ __forceinline__ float dot16_fp8(int4 q8, int4 u8, int4 v8,
                                           const float* __restrict__ Trow) {
    float acc = 0.0f;
    const int qw[4] = {q8.x, q8.y, q8.z, q8.w};
    const int uw[4] = {u8.x, u8.y, u8.z, u8.w};
    const int vw[4] = {v8.x, v8.y, v8.z, v8.w};
#pragma unroll
    for (int j = 0; j < 4; ++j) {
        v2f ql = __builtin_amdgcn_cvt_pk_f32_fp8(qw[j], false);
        v2f qh = __builtin_amdgcn_cvt_pk_f32_fp8(qw[j], true);
        v2f ul = __builtin_amdgcn_cvt_pk_f32_fp8(uw[j], false);
        v2f uh = __builtin_amdgcn_cvt_pk_f32_fp8(uw[j], true);
        v2f vl = __builtin_amdgcn_cvt_pk_f32_fp8(vw[j], false);
        v2f vh = __builtin_amdgcn_cvt_pk_f32_fp8(vw[j], true);
        const float4 tw = *(const float4*)(Trow + 4 * j);
        acc += ql.x * ul.x * vl.x * tw.x + ql.y * ul.y * vl.y * tw.y +
               qh.x * uh.x * vh.x * tw.z + qh.y * uh.y * vh.y * tw.w;
    }
    return acc;
}

__global__ void me_motif_8(const int* __restrict__ c3, const int* __restrict__ u3,
                           const int* __restrict__ v3, const int* __restrict__ tt,
                           const int4* __restrict__ Q8, const int4* __restrict__ K8,
                           const float* __restrict__ Tp, const float* __restrict__ scal,
                           float* __restrict__ sums, int nr, int M) {
    int tid = blockIdx.x * blockDim.x + threadIdx.x;
    int m = tid >> 2;
    if (m >= M) return;
    int k = tid & 3;   // r index

    int c = c3[m], u = u3[m], v = v3[m], t = tt[m];
    float bscale = scal[0];
    float* srep = sums + (size_t)(blockIdx.x & (REP - 1)) * nr;

    int4 q8 = Q8[(size_t)c * 4 + k];
    int4 u8 = K8[(size_t)u * 4 + k];
    int4 v8 = K8[(size_t)v * 4 + k];

    float p = dot16_fp8(q8, u8, v8, Tp + (size_t)t * DD);
    atomicAdd(&srep[c * RR + k], __expf(bscale * p));
}

// fp32 fallback (only if ws too small for fp8 images + replicas)
__global__ void me_motif_f32(const int* __restrict__ c3, const int* __restrict__ u3,
                             const int* __restrict__ v3, const int* __restrict__ tt,
                             const float* __restrict__ Q3, const float* __restrict__ K3,
                             const float* __restrict__ Tp, const float* __restrict__ scal,
                             float* __restrict__ sums, int M) {
    int tid = blockIdx.x * blockDim.x + threadIdx.x;
    int m = tid >> 4;
    if (m >= M) return;
    int l = tid & 15;
    int r = l >> 2;
    int off = r * DD + ((l & 3) << 2);
    int dc  = (l & 3) << 2;

    int c = c3[m], u = u3[m], v = v3[m], t = tt[m];
    float bscale = scal[0];

    const float4 q  = *(const float4*)(Q3 + ((size_t)c * (RR * DD) + off));
    const float4 ku = *(const float4*)(K3 + ((size_t)u * (RR * DD) + off));
    const float4 kv = *(const float4*)(K3 + ((size_t)v * (RR * DD) + off));
    const float4 tw = *(const float4*)(Tp + ((size_t)t * DD + dc));

    float p = q.x * ku.x * kv.x * tw.x + q.y * ku.y * kv.y * tw.y +
              q.z * ku.z * kv.z * tw.z + q.w * ku.w * kv.w * tw.w;
    p += __shfl_xor(p, 1);
    p += __shfl_xor(p, 2);

    if ((l & 3) == 0) atomicAdd(&sums[c * RR + r], __expf(bscale * p));
}

__global__ void me_init_f32(const float* __restrict__ raw_lam,
                            const float* __restrict__ raw_beta,
                            float* __restrict__ scal, float* __restrict__ sums,
                            float* __restrict__ out, int nr, int out_size) {
    int i = blockIdx.x * blockDim.x + threadIdx.x;
    if (i == 0) {
        float beta = fminf(softplus_f(raw_beta[0]), BETA_MAX);
        float lam  = softplus_f(raw_lam[0]);
        scal[0] = beta * 0.125f;
        scal[1] = lam / beta;
    }
    if (i < nr) sums[i] = 0.0f;
    if (i < out_size) out[i] = 0.0f;
}

// per-(node,r): s = sum over replicas, lse = log(s); LDS graph accumulate.
template <int NREP>
__global__ void me_node(const float* __restrict__ sums, const int* __restrict__ batch,
                        const float* __restrict__ scal, float* __restrict__ out,
                        int N, int nr, int out_size) {
    extern __shared__ float acc[];
    for (int i = threadIdx.x; i < out_size; i += blockDim.x) acc[i] = 0.0f;
    __syncthreads();

    int total = N * RR;
    for (int tid = blockIdx.x * blockDim.x + threadIdx.x; tid < total;
         tid += gridDim.x * blockDim.x) {
        int n = tid >> 2, r = tid & 3;
        float s = 0.0f;
#pragma unroll
        for (int k = 0; k < NREP; ++k) s += sums[(size_t)k * nr + tid];
        if (s > 0.0f) atomicAdd(&acc[batch[n] * RR + r], logf(s));
    }
    __syncthreads();

    float coef = scal[1];
    for (int i = threadIdx.x; i < out_size; i += blockDim.x) {
        float a = acc[i];
        if (a != 0.0f) atomicAdd(&out[i], a * coef);
    }
}

extern "C" void kernel_launch(void* const* d_in, const int* in_sizes, int n_in,
                              void* d_out, int out_size, void* d_ws, size_t ws_size,
                              hipStream_t stream) {
    const int*   c3    = (const int*)d_in[0];
    const int*   u3    = (const int*)d_in[1];
    const int*   v3    = (const int*)d_in[2];
    const int*   tt    = (const int*)d_in[3];
    const int*   batch = (const int*)d_in[4];
    const float* Q3    = (const float*)d_in[5];
    const float* K3    = (const float*)d_in[6];
    const float* Tp    = (const float*)d_in[7];
    const float* rlam  = (const float*)d_in[8];
    const float* rbeta = (const float*)d_in[9];

    const int M   = in_sizes[0];
    const int nel = in_sizes[5];          // N*R*D floats per array
    const int N   = nel / (RR * DD);
    const int nr  = N * RR;
    const int nrep = nr * REP;

    const size_t fp8_bytes = (size_t)nel;                 // 1 B/elem per array
    const size_t need = 2 * fp8_bytes + (2 + (size_t)nrep) * sizeof(float);

    float* out = (float*)d_out;

    if (ws_size >= need) {
        int4*  Q8   = (int4*)d_ws;
        int4*  K8   = (int4*)((char*)d_ws + fp8_bytes);
        float* scal = (float*)((char*)d_ws + 2 * fp8_bytes);
        float* sums = scal + 2;

        const int n16each = nel / 16;
        {
            int tot = 2 * n16each;
            if (nrep > tot) tot = nrep;
            if (out_size > tot) tot = out_size;
            me_init_convert<<<(tot + 255) / 256, 256, 0, stream>>>(
                rlam, rbeta, Q3, K3, Q8, K8, scal, sums, out, n16each, nrep, out_size);
        }
        {
            long long threads = (long long)M * 4;
            int blocks = (int)((threads + 255) / 256);
            me_motif_8<<<blocks, 256, 0, stream>>>(c3, u3, v3, tt, Q8, K8, Tp, scal,
                                                   sums, nr, M);
        }
        me_node<REP><<<256, 256, (size_t)out_size * sizeof(float), stream>>>(
            sums, batch, scal, out, N, nr, out_size);
    } else {
        float* scal = (float*)d_ws;
        float* sums = scal + 2;
        {
            int tot = nr > out_size ? nr : out_size;
            me_init_f32<<<(tot + 255) / 256, 256, 0, stream>>>(rlam, rbeta, scal, sums, out, nr, out_size);
        }
        {
            long long threads = (long long)M * 16;
            int blocks = (int)((threads + 255) / 256);
            me_motif_f32<<<blocks, 256, 0, stream>>>(c3, u3, v3, tt, Q3, K3, Tp, scal, sums, M);
        }
        me_node<1><<<256, 256, (size_t)out_size * sizeof(float), stream>>>(
            sums, batch, scal, out, N, nr, out_size);
    }
}